// Round 3
// baseline (68.412 us; speedup 1.0000x reference)
//
#include <hip/hip_runtime.h>

// BertWordEmbedder: B=64, T=512, H=768, W=256, D=256
// De-fused pipeline:
//   prep_wt:     proj_w [768][256] f32 -> wt [256][768] bf16   (d_ws)
//   prep_bounds: word segment bounds[b][w] via binary search    (d_ws)
//   pool:        one WAVE per (b,w): gather tokens, mean, bf16 -> we[16384][768]
//   gemm:        [16384x768]x[768x256] MFMA, A/B direct from global, +bias
// ws layout: [0) wt 393216B | [393216) bounds 65792B | [524288) we 25165824B

#define NB 64
#define NT 512
#define NH 768
#define NW 256
#define ND 256

typedef __attribute__((ext_vector_type(8))) short short8;
typedef __attribute__((ext_vector_type(4))) float f32x4;
typedef __attribute__((ext_vector_type(4))) float float4v;
typedef __attribute__((ext_vector_type(4))) unsigned short ushort4v;

__device__ __forceinline__ unsigned short f2bf(float f) {
    union { float f; unsigned u; } v; v.f = f;
    unsigned r = v.u + 0x7fffu + ((v.u >> 16) & 1u);  // RNE
    return (unsigned short)(r >> 16);
}

// proj_w [H][D] fp32 -> wt [D][H] bf16
__global__ void prep_wt(const float* __restrict__ w, unsigned short* __restrict__ wt) {
    __shared__ float tile[32][33];
    int tx = threadIdx.x & 31, ty = threadIdx.x >> 5;
    int k0 = blockIdx.x * 32, n0 = blockIdx.y * 32;
    #pragma unroll
    for (int i = 0; i < 4; ++i)
        tile[ty + 8 * i][tx] = w[(size_t)(k0 + ty + 8 * i) * ND + n0 + tx];
    __syncthreads();
    #pragma unroll
    for (int i = 0; i < 4; ++i)
        wt[(size_t)(n0 + ty + 8 * i) * NH + k0 + tx] = f2bf(tile[tx][ty + 8 * i]);
}

// bounds[b][w] = lower_bound(wid[b,:], w), w in [0, NW]; stride NW+1
__global__ void prep_bounds(const int* __restrict__ wid, int* __restrict__ bounds) {
    __shared__ int s[NT];
    int b = blockIdx.x, tid = threadIdx.x;
    s[tid]       = wid[b * NT + tid];
    s[tid + 256] = wid[b * NT + tid + 256];
    __syncthreads();
    for (int w = tid; w <= NW; w += 256) {
        int lo = 0, hi = NT;
        while (lo < hi) { int m = (lo + hi) >> 1; if (s[m] < w) lo = m + 1; else hi = m; }
        bounds[b * (NW + 1) + w] = lo;
    }
}

// one wave per (b,w): mean of token rows -> bf16 we row
__global__ __launch_bounds__(256) void pool(const float* __restrict__ hs,
                                            const int* __restrict__ bounds,
                                            unsigned short* __restrict__ we) {
    const int wave = threadIdx.x >> 6, lane = threadIdx.x & 63;
    const int idx = blockIdx.x * 4 + wave;           // 0..16383
    const int b = idx >> 8, w = idx & 255;
    int s = __builtin_amdgcn_readfirstlane(bounds[b * (NW + 1) + w]);
    int e = __builtin_amdgcn_readfirstlane(bounds[b * (NW + 1) + w + 1]);

    const float* base = hs + (size_t)b * NT * NH + lane * 4;
    float4v a0 = {0,0,0,0}, a1 = {0,0,0,0}, a2 = {0,0,0,0};

    int t = s;
    for (; t + 2 <= e; t += 2) {                     // 6 loads in flight
        const float* p0 = base + (size_t)t * NH;
        const float* p1 = base + (size_t)(t + 1) * NH;
        float4v x0 = *(const float4v*)(p0);
        float4v x1 = *(const float4v*)(p0 + 256);
        float4v x2 = *(const float4v*)(p0 + 512);
        float4v y0 = *(const float4v*)(p1);
        float4v y1 = *(const float4v*)(p1 + 256);
        float4v y2 = *(const float4v*)(p1 + 512);
        #pragma unroll
        for (int j = 0; j < 4; ++j) {
            a0[j] += x0[j] + y0[j]; a1[j] += x1[j] + y1[j]; a2[j] += x2[j] + y2[j];
        }
    }
    if (t < e) {
        const float* p0 = base + (size_t)t * NH;
        float4v x0 = *(const float4v*)(p0);
        float4v x1 = *(const float4v*)(p0 + 256);
        float4v x2 = *(const float4v*)(p0 + 512);
        #pragma unroll
        for (int j = 0; j < 4; ++j) { a0[j] += x0[j]; a1[j] += x1[j]; a2[j] += x2[j]; }
    }

    int cnt = e - s; if (cnt < 1) cnt = 1;
    float sc = 1.0f / (float)cnt;
    unsigned short* dst = we + (size_t)idx * NH + lane * 4;
    ushort4v u0, u1, u2;
    #pragma unroll
    for (int j = 0; j < 4; ++j) {
        u0[j] = f2bf(a0[j] * sc); u1[j] = f2bf(a1[j] * sc); u2[j] = f2bf(a2[j] * sc);
    }
    *(ushort4v*)(dst)       = u0;
    *(ushort4v*)(dst + 256) = u1;
    *(ushort4v*)(dst + 512) = u2;
}

// [16384 x 768] x [768 x 256] + bias -> out fp32. 8 waves: wave = (mh, nq),
// 32x64 out tile each. A,B frags read DIRECT from global (no LDS).
__global__ __launch_bounds__(512, 2)
void gemm(const unsigned short* __restrict__ we, const unsigned short* __restrict__ wt,
          const float* __restrict__ bias, float* __restrict__ out) {
    const int tid = threadIdx.x, wave = tid >> 6, lane = tid & 63;
    const int nq = wave & 3, mh = wave >> 2;
    const int cl = lane & 15, kg = lane >> 4;
    const size_t r0 = (size_t)blockIdx.x * 64 + mh * 32;
    const int c0 = nq * 64;

    const unsigned short* ap[2];
    const unsigned short* bp[4];
    #pragma unroll
    for (int mt = 0; mt < 2; ++mt) ap[mt] = we + (r0 + mt * 16 + cl) * NH + kg * 8;
    #pragma unroll
    for (int nt = 0; nt < 4; ++nt) bp[nt] = wt + (size_t)(c0 + nt * 16 + cl) * NH + kg * 8;

    f32x4 acc[2][4];
    #pragma unroll
    for (int mt = 0; mt < 2; ++mt)
        #pragma unroll
        for (int nt = 0; nt < 4; ++nt)
            #pragma unroll
            for (int r = 0; r < 4; ++r) acc[mt][nt][r] = 0.f;

    #pragma unroll 4
    for (int ks = 0; ks < NH / 32; ++ks) {           // 24 K-steps
        short8 a[2], bf[4];
        #pragma unroll
        for (int mt = 0; mt < 2; ++mt) a[mt] = *(const short8*)(ap[mt] + ks * 32);
        #pragma unroll
        for (int nt = 0; nt < 4; ++nt) bf[nt] = *(const short8*)(bp[nt] + ks * 32);
        #pragma unroll
        for (int mt = 0; mt < 2; ++mt)
            #pragma unroll
            for (int nt = 0; nt < 4; ++nt)
                acc[mt][nt] = __builtin_amdgcn_mfma_f32_16x16x32_bf16(a[mt], bf[nt], acc[mt][nt], 0, 0, 0);
    }

    float bv[4];
    #pragma unroll
    for (int nt = 0; nt < 4; ++nt) bv[nt] = bias[c0 + nt * 16 + cl];

    #pragma unroll
    for (int mt = 0; mt < 2; ++mt)
        #pragma unroll
        for (int nt = 0; nt < 4; ++nt)
            #pragma unroll
            for (int r = 0; r < 4; ++r)
                out[(r0 + mt * 16 + kg * 4 + r) * ND + c0 + nt * 16 + cl] = acc[mt][nt][r] + bv[nt];
}

extern "C" void kernel_launch(void* const* d_in, const int* in_sizes, int n_in,
                              void* d_out, int out_size, void* d_ws, size_t ws_size,
                              hipStream_t stream) {
    const float* hs  = (const float*)d_in[0];
    const int*   wid = (const int*)d_in[1];
    const float* pw  = (const float*)d_in[2];
    const float* pb  = (const float*)d_in[3];
    float* out = (float*)d_out;

    unsigned short* wt = (unsigned short*)d_ws;                          // 393216 B
    int* bounds        = (int*)((char*)d_ws + 393216);                   // 65792 B
    unsigned short* we = (unsigned short*)((char*)d_ws + 524288);        // 25165824 B

    dim3 gp(NH / 32, ND / 32);
    prep_wt<<<gp, 256, 0, stream>>>(pw, wt);
    prep_bounds<<<NB, 256, 0, stream>>>(wid, bounds);
    pool<<<NB * NW / 4, 256, 0, stream>>>(hs, bounds, we);
    gemm<<<NB * NW / 64, 512, 0, stream>>>(we, wt, pb, out);
}